// Round 1
// 4803.706 us; speedup vs baseline: 1.0801x; 1.0801x over previous
//
#include <hip/hip_runtime.h>
#include <cstdint>
#include <cstddef>

#define SEQ   512
#define BATCH 128
#define EMB   1024
#define HID   1024
#define VOCAB 50257
#define GATES 4096  // 4*HID

typedef _Float16 f16x8 __attribute__((ext_vector_type(8)));
typedef float    f32x4 __attribute__((ext_vector_type(4)));
typedef unsigned short u16;
typedef u16 u16x8 __attribute__((ext_vector_type(8)));  // 16-byte transfer unit

__device__ inline u16 f2h(float x) { union { _Float16 h; u16 u; } c; c.h = (_Float16)x; return c.u; }
__device__ inline float h2f(u16 u) { union { u16 u; _Float16 h; } c; c.u = u; return (float)c.h; }

// ---------------- prep kernels ----------------
__global__ void cast_f32_f16_kernel(const float* __restrict__ src, u16* __restrict__ dst, int n4) {
  int i = blockIdx.x * blockDim.x + threadIdx.x;
  int stride = gridDim.x * blockDim.x;
  for (; i < n4; i += stride) {
    float4 v = ((const float4*)src)[i];
    ushort4 o;
    o.x = f2h(v.x); o.y = f2h(v.y); o.z = f2h(v.z); o.w = f2h(v.w);
    ((ushort4*)dst)[i] = o;
  }
}

__global__ void init_kernel(const float* __restrict__ bih, const float* __restrict__ bhh,
                            float* __restrict__ bias, u16* __restrict__ h0, int* __restrict__ sync) {
  int i = blockIdx.x * blockDim.x + threadIdx.x;  // grid 128x256 = 32768
  if (i < GATES) bias[i] = bih[i] + bhh[i];
  ushort4 z; z.x = z.y = z.z = z.w = 0;
  ((ushort4*)h0)[i] = z;                          // 32768*4 = 131072 u16 = h slot 0
  if (i < 8192) sync[i] = 0;                      // flags (128x32 ints)
}

// ---------------- big GEMM: gates_x[t][b][n] = emb[X[t,b]] . W_ih[n] ----------------
// 128x128 tile, BK=32, fused embedding gather. Explicit VGPR->LDS staging (16B units).
// Output layout now [t][b][n] (b-major) so the LSTM epilogue lane (1 b x 4 j) reads ushort4.
__global__ __launch_bounds__(256) void embed_gemm(
    const u16* __restrict__ embw, const u16* __restrict__ wih,
    const int* __restrict__ X, u16* __restrict__ gx, int t0)
{
  __shared__ u16 Als[4096];
  __shared__ u16 Bls[4096];
  const int tid = threadIdx.x;
  const int w = tid >> 6, lane = tid & 63;
  const int T = t0 + blockIdx.y;
  const int colbase = blockIdx.x << 7;
  const int wm = w & 1, wn = w >> 1;
  f32x4 acc[4][4] = {};
  const u16* afp = Als + (lane >> 4) * 1024 + (wm * 64 + (lane & 15)) * 8;
  const u16* bfp = Bls + (lane >> 4) * 1024 + (wn * 64 + (lane & 15)) * 8;

  // staging slots (16B each): idx = s*256+tid; bits: [9]=half(A/B), [8:7]=kq, [6:0]=row
  int skq[4], srow[4], shalf[4];
  size_t sg[4];
#pragma unroll
  for (int s = 0; s < 4; ++s) {
    const int idx = s * 256 + tid;
    shalf[s] = idx >> 9; skq[s] = (idx >> 7) & 3; srow[s] = idx & 127;
    if (shalf[s] == 0) sg[s] = (size_t)X[(size_t)T * BATCH + srow[s]] * EMB + skq[s] * 8;
    else               sg[s] = (size_t)(colbase + srow[s]) * EMB + skq[s] * 8;
  }

  for (int kit = 0; kit < 32; ++kit) {
    u16x8 v[4];
#pragma unroll
    for (int s = 0; s < 4; ++s)
      v[s] = *(const u16x8*)((shalf[s] ? wih : embw) + sg[s] + kit * 32);
#pragma unroll
    for (int s = 0; s < 4; ++s)
      *(u16x8*)((shalf[s] ? Bls : Als) + skq[s] * 1024 + srow[s] * 8) = v[s];
    __syncthreads();
    f16x8 af[4], bf[4];
#pragma unroll
    for (int mt = 0; mt < 4; ++mt) af[mt] = *(const f16x8*)(afp + mt * 128);
#pragma unroll
    for (int nt = 0; nt < 4; ++nt) bf[nt] = *(const f16x8*)(bfp + nt * 128);
#pragma unroll
    for (int mt = 0; mt < 4; ++mt)
#pragma unroll
      for (int nt = 0; nt < 4; ++nt)
        acc[mt][nt] = __builtin_amdgcn_mfma_f32_16x16x32_f16(af[mt], bf[nt], acc[mt][nt], 0, 0, 0);
    __syncthreads();
  }
  // store C as fp16, layout [t_local][b][n]; C/D map: col(n)=lane&15, row(b)=(lane>>4)*4+reg
  const size_t outbase = (size_t)blockIdx.y * ((size_t)GATES * BATCH);
#pragma unroll
  for (int mt = 0; mt < 4; ++mt) {
#pragma unroll
    for (int nt = 0; nt < 4; ++nt) {
      const int n  = colbase + wn * 64 + nt * 16 + (lane & 15);
      const int b0 = wm * 64 + mt * 16 + ((lane >> 4) << 2);
#pragma unroll
      for (int p = 0; p < 4; ++p)
        gx[outbase + (size_t)(b0 + p) * GATES + n] = f2h(acc[mt][nt][p]);
    }
  }
}

// ---------------- persistent LSTM recurrence (operand-swapped, K-split) ----------------
// 128 WGs: blockIdx = (jw<<1)|bh. WG owns batch-half bh (64 rows), j-slice [jw*16,+16).
// MFMA: A = W (M=16 j, REGISTER-RESIDENT: 4g x 8ks x 4 VGPR = 128 VGPRs/wave),
//       B = h (N=16 batch, read directly from the ring buffer), D[m=j][n=b].
// Wave w owns k-quarter [w*256, +256) -> per-step cross-wave K-reduction via LDS.
// h ring slot layout [jb=j>>3][b][j8]; stores are relaxed agent-scope (write-through
// to LLC); readers always touch VIRGIN ring lines -> fresh LLC data.
//
// SYNC (new this round): no global 128-WG barrier. Each producer WG publishes its
// per-WG flag IMMEDIATELY after its h stores are LLC-acked (explicit s_waitcnt
// vmcnt(0) + raw s_barrier) and BEFORE the gx HBM prefetch is issued, so the flag
// is no longer delayed by an HBM round-trip drain. Each consumer wave w polls only
// the 16 producer flags (jw' in [w*16,w*16+16), same bh) whose h-chunks it actually
// reads. Flags are monotonic step counters -> per-step dependency DAG, no deadlock.
// The two batch-halves are now fully decoupled.
__global__ __launch_bounds__(256, 1) void lstm_kernel(
    const u16* __restrict__ whh, const float* __restrict__ bias,
    const u16* __restrict__ gx, u16* __restrict__ hring,
    float* __restrict__ cstate, float* __restrict__ hlast,
    int* __restrict__ flags, int t0, int t1)
{
  extern __shared__ u16 LdsRaw[];
  f32x4* Red = (f32x4*)LdsRaw;   // [w(4)][g(4)][nt(4)][lane(64)] f32x4 = 64 KB
  const int tid = threadIdx.x;
  const int w = tid >> 6, lane = tid & 63;
  const int jloc = lane & 15, lq = lane >> 4;
  const int bh = blockIdx.x & 1;
  const int jw = blockIdx.x >> 1;

  // persistent A-operand: W slice in registers. A[m=jloc][k = w*256 + ks*32 + lq*8 +0..7]
  f16x8 wreg[4][8];
#pragma unroll
  for (int g = 0; g < 4; ++g)
#pragma unroll
    for (int ks = 0; ks < 8; ++ks)
      wreg[g][ks] = *(const f16x8*)(whh + ((size_t)g * HID + jw * 16 + jloc) * HID
                                          + w * 256 + ks * 32 + lq * 8);

  const int b  = bh * 64 + w * 16 + jloc;   // epilogue-owned batch row
  const int j0 = jw * 16 + lq * 4;          // epilogue-owned j base (4 consecutive j)
  f32x4 bs[4];
#pragma unroll
  for (int g = 0; g < 4; ++g) bs[g] = *(const f32x4*)(bias + g * HID + j0);

  f32x4 cc;
  if (t0 == 0) { cc[0] = cc[1] = cc[2] = cc[3] = 0.f; }
  else cc = *(const f32x4*)(cstate + (size_t)b * HID + j0);

  // B-load base: jb = w*32 + ks*4 + lq ; b' = bh*64 + nt*16 + jloc
  const u16* hb = hring + (size_t)(w * 32 + lq) * 1024 + (size_t)(bh * 64 + jloc) * 8;
  // h-store index: 4 consecutive j within one octet -> one 8B store
  const int hw_idx = (jw * 2 + (lq >> 1)) * 1024 + b * 8 + (lq & 1) * 4;
  // gx per-lane base (u16 idx): [t][b][g*1024 + j0]
  const u16* gbase = gx + (size_t)b * GATES + j0;
  // producer flags this wave depends on: jw' = w*16 + (lane&15), same bh.
  // Producer WG id = jw'*2 + bh; flag stride 32 ints (128 B).
  const int* fpoll = flags + ((w * 16 + (lane & 15)) * 2 + bh) * 32;

  ushort4 vX[4];
#pragma unroll
  for (int g = 0; g < 4; ++g) vX[g] = *(const ushort4*)(gbase + g * 1024);

  for (int t = t0; t < t1; ++t) {
    // wait only for THIS wave's 16 producers of h[t] (chunk start: ready by launch order)
    if (t > t0) {
      for (;;) {
        int a = __hip_atomic_load(fpoll, __ATOMIC_RELAXED, __HIP_MEMORY_SCOPE_AGENT);
        if (__all(a >= t)) break;
        __builtin_amdgcn_s_sleep(1);
      }
      asm volatile("" ::: "memory");          // no load hoisting above the poll
      __builtin_amdgcn_sched_barrier(0);
    }
    const u16* ap = hb + (size_t)t * (BATCH * HID);
    // issue ALL 32 h-fragment loads back-to-back (pipelined LLC misses)
    f16x8 av[8][4];
#pragma unroll
    for (int ks = 0; ks < 8; ++ks)
#pragma unroll
      for (int nt = 0; nt < 4; ++nt)
        av[ks][nt] = *(const f16x8*)(ap + ks * 4096 + nt * 128);
    __builtin_amdgcn_sched_barrier(0);
    f32x4 acc[4][4] = {};
#pragma unroll
    for (int ks = 0; ks < 8; ++ks)
#pragma unroll
      for (int g = 0; g < 4; ++g)
#pragma unroll
        for (int nt = 0; nt < 4; ++nt)
          acc[g][nt] = __builtin_amdgcn_mfma_f32_16x16x32_f16(wreg[g][ks], av[ks][nt], acc[g][nt], 0, 0, 0);
    // cross-wave K reduction: wave w consumes nt==w outputs
#pragma unroll
    for (int g = 0; g < 4; ++g)
#pragma unroll
      for (int nt = 0; nt < 4; ++nt)
        if (nt != w) Red[((w * 4 + g) * 4 + nt) * 64 + lane] = acc[g][nt];
    __syncthreads();
    f32x4 gate[4];
#pragma unroll
    for (int g = 0; g < 4; ++g) {
      gate[g] = acc[g][w];
#pragma unroll
      for (int wp = 0; wp < 4; ++wp)
        if (wp != w) gate[g] += Red[((wp * 4 + g) * 4 + w) * 64 + lane];
    }
    u16* hout = hring + (size_t)(t + 1) * (BATCH * HID);
    float hn4[4];
#pragma unroll
    for (int p = 0; p < 4; ++p) {
      float gi = gate[0][p] + h2f(((const u16*)&vX[0])[p]) + bs[0][p];
      float gf = gate[1][p] + h2f(((const u16*)&vX[1])[p]) + bs[1][p];
      float gg = gate[2][p] + h2f(((const u16*)&vX[2])[p]) + bs[2][p];
      float go = gate[3][p] + h2f(((const u16*)&vX[3])[p]) + bs[3][p];
      float ii = 1.f / (1.f + __expf(-gi));
      float ff = 1.f / (1.f + __expf(-gf));
      float e2 = __expf(-2.f * fabsf(gg));
      float tg = copysignf((1.f - e2) / (1.f + e2), gg);
      float oo = 1.f / (1.f + __expf(-go));
      float cn = ff * cc[p] + ii * tg;
      cc[p] = cn;
      float e2c = __expf(-2.f * fabsf(cn));
      float tc = copysignf((1.f - e2c) / (1.f + e2c), cn);
      hn4[p] = oo * tc;
    }
    unsigned long long hp = (unsigned long long)f2h(hn4[0])
                          | ((unsigned long long)f2h(hn4[1]) << 16)
                          | ((unsigned long long)f2h(hn4[2]) << 32)
                          | ((unsigned long long)f2h(hn4[3]) << 48);
    __hip_atomic_store((unsigned long long*)(hout + hw_idx), hp,
                       __ATOMIC_RELAXED, __HIP_MEMORY_SCOPE_AGENT);
    if (t + 1 == SEQ) {
      float4 hl; hl.x = hn4[0]; hl.y = hn4[1]; hl.z = hn4[2]; hl.w = hn4[3];
      *(float4*)(hlast + (size_t)b * HID + j0) = hl;
    }
    // drain ONLY the h stores (gx prefetch not yet issued), then raw WG barrier:
    // all 4 waves' h-chunks are LLC-visible and all Red reads of this step are done.
    asm volatile("s_waitcnt vmcnt(0)" ::: "memory");
    __builtin_amdgcn_sched_barrier(0);
    __builtin_amdgcn_s_barrier();
    if (t + 1 < t1) {
      // publish FIRST (critical path), prefetch gx AFTER (overlaps next poll+MFMA)
      if (tid == 0)
        __hip_atomic_store(flags + blockIdx.x * 32, t + 1,
                           __ATOMIC_RELAXED, __HIP_MEMORY_SCOPE_AGENT);
      const size_t off = (size_t)(t + 1 - t0) * ((size_t)GATES * BATCH);
#pragma unroll
      for (int g = 0; g < 4; ++g) vX[g] = *(const ushort4*)(gbase + off + g * 1024);
    }
  }
  *(f32x4*)(cstate + (size_t)b * HID + j0) = cc;
}

// ---------------- log_softmax over BATCH axis ----------------
__global__ void logsoftmax_kernel(const float* __restrict__ hlast, float* __restrict__ out) {
  const int j = blockIdx.x * blockDim.x + threadIdx.x;
  if (j >= HID) return;
  float m = -1e30f;
  for (int b = 0; b < BATCH; ++b) m = fmaxf(m, hlast[(size_t)b * HID + j]);
  float s = 0.f;
  for (int b = 0; b < BATCH; ++b) s += expf(hlast[(size_t)b * HID + j] - m);
  const float lse = m + logf(s);
  for (int b = 0; b < BATCH; ++b) out[(size_t)b * HID + j] = hlast[(size_t)b * HID + j] - lse;
}

// ---------------- host ----------------
extern "C" void kernel_launch(void* const* d_in, const int* in_sizes, int n_in,
                              void* d_out, int out_size, void* d_ws, size_t ws_size,
                              hipStream_t stream) {
  const int*   X    = (const int*)d_in[0];
  const float* embd = (const float*)d_in[1];
  const float* wih  = (const float*)d_in[2];
  const float* whh  = (const float*)d_in[3];
  const float* bih  = (const float*)d_in[4];
  const float* bhh  = (const float*)d_in[5];
  float* out = (float*)d_out;

  char* p = (char*)d_ws;
  auto alloc = [&](size_t bytes) { char* r = p; p += (bytes + 255) & ~(size_t)255; return r; };
  u16*   embw    = (u16*)alloc((size_t)VOCAB * EMB * 2);
  u16*   wihh    = (u16*)alloc((size_t)GATES * EMB * 2);
  u16*   whhh    = (u16*)alloc((size_t)GATES * HID * 2);
  float* bias    = (float*)alloc((size_t)GATES * 4);
  u16*   hring   = (u16*)alloc((size_t)(SEQ + 1) * BATCH * HID * 2);
  float* hlast   = (float*)alloc((size_t)BATCH * HID * 4);
  float* cst     = (float*)alloc((size_t)BATCH * HID * 4);
  int*   flags   = (int*)alloc(32768);   // 128 flags at 128B stride
  size_t used = (size_t)(p - (char*)d_ws);
  size_t avail = ws_size > used ? ws_size - used : 0;
  long long Tc = (long long)(avail / ((size_t)GATES * BATCH * 2));
  if (Tc > SEQ) Tc = SEQ;
  if (Tc < 1) return;  // insufficient workspace
  u16* gx = (u16*)alloc((size_t)Tc * GATES * BATCH * 2);

  hipFuncSetAttribute((const void*)lstm_kernel, hipFuncAttributeMaxDynamicSharedMemorySize, 65536);

  cast_f32_f16_kernel<<<2048, 256, 0, stream>>>(embd, embw, VOCAB * EMB / 4);
  cast_f32_f16_kernel<<<256, 256, 0, stream>>>(wih, wihh, GATES * EMB / 4);
  cast_f32_f16_kernel<<<256, 256, 0, stream>>>(whh, whhh, GATES * HID / 4);
  init_kernel<<<128, 256, 0, stream>>>(bih, bhh, bias, hring, flags);
  for (int t0 = 0; t0 < SEQ; t0 += (int)Tc) {
    const int t1 = (t0 + (int)Tc < SEQ) ? t0 + (int)Tc : SEQ;
    dim3 grid(32, t1 - t0);
    embed_gemm<<<grid, 256, 0, stream>>>(embw, wihh, X, gx, t0);
    lstm_kernel<<<128, 256, 65536, stream>>>(whhh, bias, gx, hring, cst, hlast, flags, t0, t1);
  }
  logsoftmax_kernel<<<4, 256, 0, stream>>>(hlast, out);
}

// Round 3
// 4011.520 us; speedup vs baseline: 1.2934x; 1.1975x over previous
//
#include <hip/hip_runtime.h>
#include <cstdint>
#include <cstddef>

#define SEQ   512
#define BATCH 128
#define EMB   1024
#define HID   1024
#define VOCAB 50257
#define GATES 4096  // 4*HID

typedef _Float16 f16x8 __attribute__((ext_vector_type(8)));
typedef float    f32x4 __attribute__((ext_vector_type(4)));
typedef unsigned short u16;
typedef u16 u16x8 __attribute__((ext_vector_type(8)));  // 16-byte transfer unit

__device__ inline u16 f2h(float x) { union { _Float16 h; u16 u; } c; c.h = (_Float16)x; return c.u; }
__device__ inline float h2f(u16 u) { union { u16 u; _Float16 h; } c; c.u = u; return (float)c.h; }

// ---------------- prep kernels ----------------
__global__ void cast_f32_f16_kernel(const float* __restrict__ src, u16* __restrict__ dst, int n4) {
  int i = blockIdx.x * blockDim.x + threadIdx.x;
  int stride = gridDim.x * blockDim.x;
  for (; i < n4; i += stride) {
    float4 v = ((const float4*)src)[i];
    ushort4 o;
    o.x = f2h(v.x); o.y = f2h(v.y); o.z = f2h(v.z); o.w = f2h(v.w);
    ((ushort4*)dst)[i] = o;
  }
}

__global__ void init_kernel(const float* __restrict__ bih, const float* __restrict__ bhh,
                            float* __restrict__ bias, u16* __restrict__ h0, int* __restrict__ sync) {
  int i = blockIdx.x * blockDim.x + threadIdx.x;  // grid 128x256 = 32768
  if (i < GATES) bias[i] = bih[i] + bhh[i];
  ushort4 z; z.x = z.y = z.z = z.w = 0;
  ((ushort4*)h0)[i] = z;                          // 32768*4 = 131072 u16 = h slot 0
  if (i < 8192) sync[i] = 0;                      // WG flags (128x32 ints) + gxcnt[512] at +4096
}

// ================= FUSED persistent kernel: 256 WGs = 256 CUs =================
// WGs 0..127  : LSTM recurrence (identical structure to round-1 lstm_kernel).
// WGs 128..255: embed+W_ih GEMM producer, t-major tile loop, publishes gxcnt[t].
// 96 KB dynamic LDS forces 1 WG/CU; grid == CU count on an otherwise-idle device
// guarantees co-residency (same property round-1's 128-WG spin-sync relied on).
// REGULAR launch (not cooperative): hipLaunchCooperativeKernel is not graph-
// capturable in this harness — that was round-2's silent failure.
// Cross-XCD same-dispatch visibility: gx stores, hlast stores = agent-scope
// write-through atomics; vX loads = agent-scope atomic loads (single-use data,
// prefetched a full step ahead -> latency hidden, no L2-reuse lost).
__global__ __launch_bounds__(256, 1) void fused_kernel(
    const u16* __restrict__ embw, const u16* __restrict__ wih,
    const u16* __restrict__ whh, const float* __restrict__ bias,
    const int* __restrict__ X, u16* __restrict__ gx,
    u16* __restrict__ hring, float* __restrict__ hlast,
    float* __restrict__ out, int* __restrict__ flags, int Tc)
{
  extern __shared__ u16 LdsRaw[];
  const int tid = threadIdx.x;
  const int w = tid >> 6, lane = tid & 63;
  int* gxcnt = flags + 4096;   // 512 step-readiness counters (each counts to 32)

  if (blockIdx.x >= 128) {
    // ---------------- producer path: gates_x[t][b][n] = emb[X[t,b]] . W_ih[n]
    u16* Als = LdsRaw;
    u16* Bls = LdsRaw + 4096;
    const int ewg = blockIdx.x - 128;
    const int wm = w & 1, wn = w >> 1;
    const u16* afp = Als + (lane >> 4) * 1024 + (wm * 64 + (lane & 15)) * 8;
    const u16* bfp = Bls + (lane >> 4) * 1024 + (wn * 64 + (lane & 15)) * 8;
    int skq[4], srow[4], shalf[4];
#pragma unroll
    for (int s = 0; s < 4; ++s) {
      const int idx = s * 256 + tid;
      shalf[s] = idx >> 9; skq[s] = (idx >> 7) & 3; srow[s] = idx & 127;
    }
    // tiles t-major: tile = T*32 + colblock; 128 WGs sweep 4 timesteps per pass
    for (int tile = ewg; tile < SEQ * 32; tile += 128) {
      const int T = tile >> 5;
      const int colbase = (tile & 31) << 7;
      // ring back-pressure: slot (T%Tc) free when every consumer passed step T-Tc
      if (T >= Tc) {
        const int need = T - Tc + 1;
        for (;;) {
          int f = __hip_atomic_load(flags + (tid & 127) * 32,
                                    __ATOMIC_RELAXED, __HIP_MEMORY_SCOPE_AGENT);
          if (__syncthreads_and(f >= need)) break;
          __builtin_amdgcn_s_sleep(8);
        }
      }
      size_t sg[4];
#pragma unroll
      for (int s = 0; s < 4; ++s) {
        if (shalf[s] == 0) sg[s] = (size_t)X[(size_t)T * BATCH + srow[s]] * EMB + skq[s] * 8;
        else               sg[s] = (size_t)(colbase + srow[s]) * EMB + skq[s] * 8;
      }
      f32x4 acc[4][4] = {};
      // depth-4 global prefetch queue (statically indexed -> stays in VGPRs)
      u16x8 vq[4][4];
#pragma unroll
      for (int d = 0; d < 4; ++d)
#pragma unroll
        for (int s = 0; s < 4; ++s)
          vq[d][s] = *(const u16x8*)((shalf[s] ? wih : embw) + sg[s] + d * 32);
      for (int kb = 0; kb < 32; kb += 4) {
#pragma unroll
        for (int d = 0; d < 4; ++d) {
#pragma unroll
          for (int s = 0; s < 4; ++s)
            *(u16x8*)((shalf[s] ? Bls : Als) + skq[s] * 1024 + srow[s] * 8) = vq[d][s];
          __syncthreads();
          if (kb + d + 4 < 32) {
#pragma unroll
            for (int s = 0; s < 4; ++s)
              vq[d][s] = *(const u16x8*)((shalf[s] ? wih : embw) + sg[s] + (kb + d + 4) * 32);
          }
          f16x8 af[4], bf[4];
#pragma unroll
          for (int mt = 0; mt < 4; ++mt) af[mt] = *(const f16x8*)(afp + mt * 128);
#pragma unroll
          for (int nt = 0; nt < 4; ++nt) bf[nt] = *(const f16x8*)(bfp + nt * 128);
#pragma unroll
          for (int mt = 0; mt < 4; ++mt)
#pragma unroll
            for (int nt = 0; nt < 4; ++nt)
              acc[mt][nt] = __builtin_amdgcn_mfma_f32_16x16x32_f16(af[mt], bf[nt], acc[mt][nt], 0, 0, 0);
          __syncthreads();
        }
      }
      // store to gx ring slot; agent-scope write-through (consumers are on other XCDs)
      const size_t outbase = (size_t)(T % Tc) * ((size_t)GATES * BATCH);
#pragma unroll
      for (int mt = 0; mt < 4; ++mt) {
#pragma unroll
        for (int nt = 0; nt < 4; ++nt) {
          const int n  = colbase + wn * 64 + nt * 16 + (lane & 15);
          const int b0 = wm * 64 + mt * 16 + ((lane >> 4) << 2);
#pragma unroll
          for (int p = 0; p < 4; ++p)
            __hip_atomic_store(gx + outbase + (size_t)(b0 + p) * GATES + n,
                               f2h(acc[mt][nt][p]),
                               __ATOMIC_RELAXED, __HIP_MEMORY_SCOPE_AGENT);
        }
      }
      asm volatile("s_waitcnt vmcnt(0)" ::: "memory");  // all this thread's stores LLC-acked
      __syncthreads();                                   // ... all threads' stores
      if (tid == 0)
        __hip_atomic_fetch_add(gxcnt + T, 1, __ATOMIC_RELAXED, __HIP_MEMORY_SCOPE_AGENT);
    }
    return;
  }

  // ---------------- consumer path: persistent LSTM recurrence ----------------
  f32x4* Red = (f32x4*)LdsRaw;   // [w(4)][g(4)][nt(4)][lane(64)] f32x4 = 64 KB
  const int jloc = lane & 15, lq = lane >> 4;
  const int bh = blockIdx.x & 1;
  const int jw = blockIdx.x >> 1;

  // persistent A-operand: W slice in registers. A[m=jloc][k = w*256 + ks*32 + lq*8 +0..7]
  f16x8 wreg[4][8];
#pragma unroll
  for (int g = 0; g < 4; ++g)
#pragma unroll
    for (int ks = 0; ks < 8; ++ks)
      wreg[g][ks] = *(const f16x8*)(whh + ((size_t)g * HID + jw * 16 + jloc) * HID
                                          + w * 256 + ks * 32 + lq * 8);

  const int b  = bh * 64 + w * 16 + jloc;   // epilogue-owned batch row
  const int j0 = jw * 16 + lq * 4;          // epilogue-owned j base (4 consecutive j)
  f32x4 bs[4];
#pragma unroll
  for (int g = 0; g < 4; ++g) bs[g] = *(const f32x4*)(bias + g * HID + j0);

  f32x4 cc; cc[0] = cc[1] = cc[2] = cc[3] = 0.f;

  // B-load base: jb = w*32 + ks*4 + lq ; b' = bh*64 + nt*16 + jloc
  const u16* hb = hring + (size_t)(w * 32 + lq) * 1024 + (size_t)(bh * 64 + jloc) * 8;
  const int hw_idx = (jw * 2 + (lq >> 1)) * 1024 + b * 8 + (lq & 1) * 4;
  const u16* gbase = gx + (size_t)b * GATES + j0;
  const int* fpoll = flags + ((w * 16 + (lane & 15)) * 2 + bh) * 32;

  // initial gx gate + prefetch (slot 0)
  int slot = 0;
  unsigned long long vXu[4];
  {
    const int* cnt = gxcnt;
    for (;;) {
      int c = __hip_atomic_load(cnt, __ATOMIC_RELAXED, __HIP_MEMORY_SCOPE_AGENT);
      if (c >= 32) break;
      __builtin_amdgcn_s_sleep(1);
    }
    asm volatile("" ::: "memory");
#pragma unroll
    for (int g = 0; g < 4; ++g)
      vXu[g] = __hip_atomic_load((const unsigned long long*)(gbase + g * 1024),
                                 __ATOMIC_RELAXED, __HIP_MEMORY_SCOPE_AGENT);
  }

  for (int t = 0; t < SEQ; ++t) {
    // wait only for THIS wave's 16 producers of h[t]
    if (t > 0) {
      for (;;) {
        int a = __hip_atomic_load(fpoll, __ATOMIC_RELAXED, __HIP_MEMORY_SCOPE_AGENT);
        if (__all(a >= t)) break;
        __builtin_amdgcn_s_sleep(1);
      }
      asm volatile("" ::: "memory");
      __builtin_amdgcn_sched_barrier(0);
    }
    const u16* ap = hb + (size_t)t * (BATCH * HID);
    f16x8 av[8][4];
#pragma unroll
    for (int ks = 0; ks < 8; ++ks)
#pragma unroll
      for (int nt = 0; nt < 4; ++nt)
        av[ks][nt] = *(const f16x8*)(ap + ks * 4096 + nt * 128);
    __builtin_amdgcn_sched_barrier(0);
    f32x4 acc[4][4] = {};
#pragma unroll
    for (int ks = 0; ks < 8; ++ks)
#pragma unroll
      for (int g = 0; g < 4; ++g)
#pragma unroll
        for (int nt = 0; nt < 4; ++nt)
          acc[g][nt] = __builtin_amdgcn_mfma_f32_16x16x32_f16(wreg[g][ks], av[ks][nt], acc[g][nt], 0, 0, 0);
    // cross-wave K reduction: wave w consumes nt==w outputs
#pragma unroll
    for (int g = 0; g < 4; ++g)
#pragma unroll
      for (int nt = 0; nt < 4; ++nt)
        if (nt != w) Red[((w * 4 + g) * 4 + nt) * 64 + lane] = acc[g][nt];
    __syncthreads();
    f32x4 gate[4];
#pragma unroll
    for (int g = 0; g < 4; ++g) {
      gate[g] = acc[g][w];
#pragma unroll
      for (int wp = 0; wp < 4; ++wp)
        if (wp != w) gate[g] += Red[((wp * 4 + g) * 4 + w) * 64 + lane];
    }
    u16* hout = hring + (size_t)(t + 1) * (BATCH * HID);
    float hn4[4];
#pragma unroll
    for (int p = 0; p < 4; ++p) {
      float gi = gate[0][p] + h2f((u16)(vXu[0] >> (16 * p))) + bs[0][p];
      float gf = gate[1][p] + h2f((u16)(vXu[1] >> (16 * p))) + bs[1][p];
      float gg = gate[2][p] + h2f((u16)(vXu[2] >> (16 * p))) + bs[2][p];
      float go = gate[3][p] + h2f((u16)(vXu[3] >> (16 * p))) + bs[3][p];
      float ii = 1.f / (1.f + __expf(-gi));
      float ff = 1.f / (1.f + __expf(-gf));
      float e2 = __expf(-2.f * fabsf(gg));
      float tg = copysignf((1.f - e2) / (1.f + e2), gg);
      float oo = 1.f / (1.f + __expf(-go));
      float cn = ff * cc[p] + ii * tg;
      cc[p] = cn;
      float e2c = __expf(-2.f * fabsf(cn));
      float tc = copysignf((1.f - e2c) / (1.f + e2c), cn);
      hn4[p] = oo * tc;
    }
    unsigned long long hp = (unsigned long long)f2h(hn4[0])
                          | ((unsigned long long)f2h(hn4[1]) << 16)
                          | ((unsigned long long)f2h(hn4[2]) << 32)
                          | ((unsigned long long)f2h(hn4[3]) << 48);
    __hip_atomic_store((unsigned long long*)(hout + hw_idx), hp,
                       __ATOMIC_RELAXED, __HIP_MEMORY_SCOPE_AGENT);
    if (t + 1 == SEQ) {  // hlast: agent-scope (read by WGs 0..3 in-dispatch)
      union { float f[2]; unsigned long long u; } pk;
      pk.f[0] = hn4[0]; pk.f[1] = hn4[1];
      __hip_atomic_store((unsigned long long*)(hlast + (size_t)b * HID + j0), pk.u,
                         __ATOMIC_RELAXED, __HIP_MEMORY_SCOPE_AGENT);
      pk.f[0] = hn4[2]; pk.f[1] = hn4[3];
      __hip_atomic_store((unsigned long long*)(hlast + (size_t)b * HID + j0 + 2), pk.u,
                         __ATOMIC_RELAXED, __HIP_MEMORY_SCOPE_AGENT);
    }
    // drain h (+hlast) stores, WG barrier, publish flag FIRST, then gated gx prefetch
    asm volatile("s_waitcnt vmcnt(0)" ::: "memory");
    __builtin_amdgcn_sched_barrier(0);
    __builtin_amdgcn_s_barrier();
    if (tid == 0)
      __hip_atomic_store(flags + blockIdx.x * 32, t + 1,
                         __ATOMIC_RELAXED, __HIP_MEMORY_SCOPE_AGENT);
    if (t + 1 < SEQ) {
      slot = (slot + 1 == Tc) ? 0 : slot + 1;
      const int* cnt = gxcnt + (t + 1);
      for (;;) {   // almost always satisfied: producers run ~3-6x faster than consumers
        int c = __hip_atomic_load(cnt, __ATOMIC_RELAXED, __HIP_MEMORY_SCOPE_AGENT);
        if (c >= 32) break;
        __builtin_amdgcn_s_sleep(1);
      }
      asm volatile("" ::: "memory");
      __builtin_amdgcn_sched_barrier(0);
      const u16* gslot = gbase + (size_t)slot * ((size_t)GATES * BATCH);
#pragma unroll
      for (int g = 0; g < 4; ++g)
        vXu[g] = __hip_atomic_load((const unsigned long long*)(gslot + g * 1024),
                                   __ATOMIC_RELAXED, __HIP_MEMORY_SCOPE_AGENT);
    }
  }

  // ---------------- fused log_softmax over BATCH axis (WGs 0..3) ----------------
  if (blockIdx.x < 4) {
    for (;;) {
      int f = __hip_atomic_load(flags + (tid & 127) * 32,
                                __ATOMIC_RELAXED, __HIP_MEMORY_SCOPE_AGENT);
      if (__syncthreads_and(f >= SEQ)) break;
      __builtin_amdgcn_s_sleep(4);
    }
    const int j = blockIdx.x * 256 + tid;
    float m = -1e30f;
    for (int b2 = 0; b2 < BATCH; ++b2) m = fmaxf(m, hlast[(size_t)b2 * HID + j]);
    float s = 0.f;
    for (int b2 = 0; b2 < BATCH; ++b2) s += expf(hlast[(size_t)b2 * HID + j] - m);
    const float lse = m + logf(s);
    for (int b2 = 0; b2 < BATCH; ++b2)
      out[(size_t)b2 * HID + j] = hlast[(size_t)b2 * HID + j] - lse;
  }
}

// ---------------- host ----------------
extern "C" void kernel_launch(void* const* d_in, const int* in_sizes, int n_in,
                              void* d_out, int out_size, void* d_ws, size_t ws_size,
                              hipStream_t stream) {
  const int*   X    = (const int*)d_in[0];
  const float* embd = (const float*)d_in[1];
  const float* wih  = (const float*)d_in[2];
  const float* whh  = (const float*)d_in[3];
  const float* bih  = (const float*)d_in[4];
  const float* bhh  = (const float*)d_in[5];
  float* out = (float*)d_out;

  char* p = (char*)d_ws;
  auto alloc = [&](size_t bytes) { char* r = p; p += (bytes + 255) & ~(size_t)255; return r; };
  u16*   embw    = (u16*)alloc((size_t)VOCAB * EMB * 2);
  u16*   wihh    = (u16*)alloc((size_t)GATES * EMB * 2);
  u16*   whhh    = (u16*)alloc((size_t)GATES * HID * 2);
  float* bias    = (float*)alloc((size_t)GATES * 4);
  u16*   hring   = (u16*)alloc((size_t)(SEQ + 1) * BATCH * HID * 2);
  float* hlast   = (float*)alloc((size_t)BATCH * HID * 4);
  int*   flags   = (int*)alloc(32768);   // 128 WG flags @128B stride + gxcnt[512] @ +16KB
  size_t used = (size_t)(p - (char*)d_ws);
  size_t avail = ws_size > used ? ws_size - used : 0;
  long long Tc = (long long)(avail / ((size_t)GATES * BATCH * 2));
  if (Tc > SEQ) Tc = SEQ;
  if (Tc < 1) return;  // insufficient workspace
  u16* gx = (u16*)alloc((size_t)Tc * GATES * BATCH * 2);
  int Tci = (int)Tc;

  hipFuncSetAttribute((const void*)fused_kernel, hipFuncAttributeMaxDynamicSharedMemorySize, 98304);

  cast_f32_f16_kernel<<<2048, 256, 0, stream>>>(embd, embw, VOCAB * EMB / 4);
  cast_f32_f16_kernel<<<256, 256, 0, stream>>>(wih, wihh, GATES * EMB / 4);
  cast_f32_f16_kernel<<<256, 256, 0, stream>>>(whh, whhh, GATES * HID / 4);
  init_kernel<<<128, 256, 0, stream>>>(bih, bhh, bias, hring, flags);

  // regular launch: 256 WGs x 96KB LDS = 1 WG/CU on 256 CUs -> all co-resident
  fused_kernel<<<dim3(256), dim3(256), 98304, stream>>>(
      embw, wihh, whhh, bias, X, gx, hring, hlast, out, flags, Tci);
}